// Round 3
// baseline (1384.211 us; speedup 1.0000x reference)
//
#include <hip/hip_runtime.h>
#include <math.h>

#define NB 16
#define NT 9
#define PLANE 65536          // 256*256
#define KAP_B 589824         // 9*PLANE  (per-batch kappa elems)
#define M_B   1179648        // 2*KAP_B
#define H_B   2359296        // 4*KAP_B

// d_out layout (floats): [0,16) x_out | [16, +9437184) kappa | then m (18874368) | then H (37748736)
#define OUT_KAP 16
#define OUT_M   9437200
#define OUT_H   28311568

__device__ __forceinline__ float sp10(float x) {
  float z = 10.0f * x;
  return (fmaxf(z, 0.0f) + log1pf(__expf(-fabsf(z)))) * 0.1f;
}

// ---------------- transpose: xg[b,t,xx,yy] = x[b,t,yy,xx] ----------------
__global__ __launch_bounds__(1024) void transpose_kernel(const float* __restrict__ x,
                                                         float* __restrict__ xg) {
  __shared__ float t_[32][33];
  const int plane = blockIdx.z;                 // b*9+t
  const float* src = x + (size_t)plane * PLANE;
  float* dst = xg + (size_t)plane * PLANE;
  const int x0 = blockIdx.x * 32, y0 = blockIdx.y * 32;
  t_[threadIdx.y][threadIdx.x] = src[(y0 + threadIdx.y) * 256 + x0 + threadIdx.x];
  __syncthreads();
  dst[(x0 + threadIdx.y) * 256 + (y0 + threadIdx.x)] = t_[threadIdx.x][threadIdx.y];
}

// ---------------- 3x3 SAME conv, 2 pixels per thread ----------------
// Block (16,16), tile 32 wide x 16 tall. Each thread computes pixels
// (y0+ty, x0+2tx) and (y0+ty, x0+2tx+1). Tile leading dim 35 (odd) keeps
// wave subgroups on alternating bank sets -> max 2-way conflict (free).
template <int IC, int OC, bool RELU_IN>
__global__ __launch_bounds__(256, 4) void conv2px(const float* __restrict__ in,
                                                  const float* __restrict__ wt,
                                                  float* __restrict__ out) {
  __shared__ float tile[IC][18][35];
  const int b = blockIdx.z;
  const int x0 = blockIdx.x * 32, y0 = blockIdx.y * 16;
  const int tx = threadIdx.x, ty = threadIdx.y;
  const int tid = ty * 16 + tx;
  const float* inb = in + (size_t)b * IC * PLANE;
  for (int idx = tid; idx < IC * 612; idx += 256) {   // 612 = 18*34 staged cols
    int ic = idx / 612;
    int rem = idx - ic * 612;
    int r = rem / 34, c = rem - r * 34;
    int gy = y0 + r - 1, gx = x0 + c - 1;
    float v = 0.f;
    if (gy >= 0 && gy < 256 && gx >= 0 && gx < 256) {
      v = inb[ic * PLANE + gy * 256 + gx];
      if (RELU_IN) v = fmaxf(v, 0.f);
    }
    tile[ic][r][c] = v;
  }
  __syncthreads();
  float acc0[OC], acc1[OC];
#pragma unroll
  for (int oc = 0; oc < OC; ++oc) { acc0[oc] = 0.f; acc1[oc] = 0.f; }
  for (int ic = 0; ic < IC; ++ic) {
    float p[3][4];
#pragma unroll
    for (int r = 0; r < 3; ++r)
#pragma unroll
      for (int c = 0; c < 4; ++c) p[r][c] = tile[ic][ty + r][2 * tx + c];
#pragma unroll
    for (int oc = 0; oc < OC; ++oc) {
      const float* w9 = wt + (oc * IC + ic) * 9;
      acc0[oc] += p[0][0] * w9[0] + p[0][1] * w9[1] + p[0][2] * w9[2]
                + p[1][0] * w9[3] + p[1][1] * w9[4] + p[1][2] * w9[5]
                + p[2][0] * w9[6] + p[2][1] * w9[7] + p[2][2] * w9[8];
      acc1[oc] += p[0][1] * w9[0] + p[0][2] * w9[1] + p[0][3] * w9[2]
                + p[1][1] * w9[3] + p[1][2] * w9[4] + p[1][3] * w9[5]
                + p[2][1] * w9[6] + p[2][2] * w9[7] + p[2][3] * w9[8];
    }
  }
  float* outb = out + (size_t)b * OC * PLANE + (y0 + ty) * 256 + x0 + 2 * tx;
#pragma unroll
  for (int oc = 0; oc < OC; ++oc) {
    float2 v2 = make_float2(acc0[oc], acc1[oc]);
    *reinterpret_cast<float2*>(&outb[oc * PLANE]) = v2;
  }
}

// ---------------- conv3 (20->54) 2px + oc z-split + IC-chunked staging ----------------
// z=0 -> ch 0..26 (kappa+m), z=1 -> ch 27..53 (H).
// LDS halved to [10][18][35] (25.2 KB), ic staged in 2 chunks -> ~2x blocks/CU.
// H epilogue: per-plane burst stores (18 consecutive 4B stores covering the
// thread's 72B region) so dirty lines fill quickly -> no partial-line
// eviction/rewrite (round-2 interleaved stores tripled WRITE_SIZE).
__global__ __launch_bounds__(512, 6) void conv3_fused(const float* __restrict__ in,
                                                      const float* __restrict__ wt,
                                                      float* __restrict__ out_kap,
                                                      float* __restrict__ out_m,
                                                      float* __restrict__ out_H) {
  __shared__ float tile[10][18][35];
  const int b = blockIdx.z;
  const int x0 = blockIdx.x * 32, y0 = blockIdx.y * 16;
  const int tx = threadIdx.x, ty = threadIdx.y;
  const int h = __builtin_amdgcn_readfirstlane((int)threadIdx.z);  // wave-uniform
  const int tid = (int)threadIdx.z * 256 + ty * 16 + tx;
  const float* inb = in + (size_t)b * 20 * PLANE;
  float acc0[27], acc1[27];
#pragma unroll
  for (int oc = 0; oc < 27; ++oc) { acc0[oc] = 0.f; acc1[oc] = 0.f; }
  const float* wh = wt + (size_t)h * 27 * 20 * 9;
  for (int cc = 0; cc < 2; ++cc) {
    if (cc) __syncthreads();                       // chunk0 compute done before overwrite
    for (int idx = tid; idx < 10 * 612; idx += 512) {
      int ic = idx / 612;
      int rem = idx - ic * 612;
      int r = rem / 34, c = rem - r * 34;
      int gy = y0 + r - 1, gx = x0 + c - 1;
      float v = 0.f;
      if (gy >= 0 && gy < 256 && gx >= 0 && gx < 256)
        v = inb[(cc * 10 + ic) * PLANE + gy * 256 + gx];
      tile[ic][r][c] = v;
    }
    __syncthreads();
    for (int ic = 0; ic < 10; ++ic) {
      float p[3][4];
#pragma unroll
      for (int r = 0; r < 3; ++r)
#pragma unroll
        for (int c = 0; c < 4; ++c) p[r][c] = tile[ic][ty + r][2 * tx + c];
#pragma unroll
      for (int oc = 0; oc < 27; ++oc) {
        const float* w9 = wh + (oc * 20 + cc * 10 + ic) * 9;
        acc0[oc] += p[0][0] * w9[0] + p[0][1] * w9[1] + p[0][2] * w9[2]
                  + p[1][0] * w9[3] + p[1][1] * w9[4] + p[1][2] * w9[5]
                  + p[2][0] * w9[6] + p[2][1] * w9[7] + p[2][2] * w9[8];
        acc1[oc] += p[0][1] * w9[0] + p[0][2] * w9[1] + p[0][3] * w9[2]
                  + p[1][1] * w9[3] + p[1][2] * w9[4] + p[1][3] * w9[5]
                  + p[2][1] * w9[6] + p[2][2] * w9[7] + p[2][3] * w9[8];
      }
    }
  }
  const int n0 = (y0 + ty) * 256 + x0 + 2 * tx;
  if (h == 0) {
    // kappa: natural layout, == sp10(p[ch 0..8])
    float* kapb = out_kap + (size_t)b * KAP_B;
#pragma unroll
    for (int t = 0; t < 9; ++t) {
      float2 v2 = make_float2(sp10(acc0[t]), sp10(acc1[t]));
      *reinterpret_cast<float2*>(&kapb[t * PLANE + n0]) = v2;
    }
    // m: natural layout, == p[ch 9..26]
    float* mb = out_m + (size_t)b * M_B;
#pragma unroll
    for (int c = 0; c < 18; ++c) {
      float2 v2 = make_float2(acc0[9 + c], acc1[9 + c]);
      *reinterpret_cast<float2*>(&mb[c * PLANE + n0]) = v2;
    }
  } else {
    // H: per (i,j) plane, flat index n*9+t; local ch 0..8=g, 9..17=vx, 18..26=vy
    float sg0[9], sg1[9];
#pragma unroll
    for (int t = 0; t < 9; ++t) { sg0[t] = sp10(acc0[t]); sg1[t] = sp10(acc1[t]); }
    float* hb = out_H + (size_t)b * H_B + (size_t)n0 * 9;
    // plane (0,0): g + vx*vx  -- 18 consecutive stores per thread (72B burst)
#pragma unroll
    for (int t = 0; t < 9; ++t) hb[t] = sg0[t] + acc0[9 + t] * acc0[9 + t];
#pragma unroll
    for (int t = 0; t < 9; ++t) hb[9 + t] = sg1[t] + acc1[9 + t] * acc1[9 + t];
    // plane (0,1): vx*vy
#pragma unroll
    for (int t = 0; t < 9; ++t) hb[KAP_B + t] = acc0[9 + t] * acc0[18 + t];
#pragma unroll
    for (int t = 0; t < 9; ++t) hb[KAP_B + 9 + t] = acc1[9 + t] * acc1[18 + t];
    // plane (1,0): vx*vy
#pragma unroll
    for (int t = 0; t < 9; ++t) hb[2 * KAP_B + t] = acc0[9 + t] * acc0[18 + t];
#pragma unroll
    for (int t = 0; t < 9; ++t) hb[2 * KAP_B + 9 + t] = acc1[9 + t] * acc1[18 + t];
    // plane (1,1): g + vy*vy
#pragma unroll
    for (int t = 0; t < 9; ++t) hb[3 * KAP_B + t] = sg0[t] + acc0[18 + t] * acc0[18 + t];
#pragma unroll
    for (int t = 0; t < 9; ++t) hb[3 * KAP_B + 9 + t] = sg1[t] + acc1[18 + t] * acc1[18 + t];
  }
}

// ---------------- fused M.M: w = M(xg) on 18x18 halo tile (LDS), v = M(w) on
// 16x16 center, x_out accumulated. Eliminates the w HBM round-trip and the
// second full kap/m/H pass (v-stage re-reads are L2-hot). w is zero-masked
// outside the image to match the reference's zero-padding of w in _derivs. ----
__global__ __launch_bounds__(256) void m_fused(const float* __restrict__ xgp,
                                               const float* __restrict__ dout,
                                               float* __restrict__ xsum) {
  __shared__ float ux[9][20][21];    // xg, halo 2: covers X0-2..X0+17, Y0-2..Y0+17
  __shared__ float wsd[9][18][19];   // w,  halo 1: covers X0-1..X0+16, Y0-1..Y0+16
  __shared__ float red[256];
  const int b = blockIdx.z;
  const int X0 = blockIdx.y * 16;  // xx tile
  const int Y0 = blockIdx.x * 16;  // yy tile
  const int tx = threadIdx.x, ty = threadIdx.y;
  const int tid = ty * 16 + tx;
  const float* ub = xgp + (size_t)b * 9 * PLANE;
  const float* kap_base = dout + OUT_KAP + (size_t)b * KAP_B;
  const float* m_base   = dout + OUT_M + (size_t)b * M_B;
  const float* h_base   = dout + OUT_H + (size_t)b * H_B;

  for (int idx = tid; idx < 9 * 400; idx += 256) {
    int t = idx / 400;
    int rem = idx - t * 400;
    int r = rem / 20, c = rem - r * 20;
    int xx = X0 + r - 2, yy = Y0 + c - 2;
    float v = 0.f;
    if (xx >= 0 && xx < 256 && yy >= 0 && yy < 256)
      v = ub[t * PLANE + xx * 256 + yy];
    ux[t][r][c] = v;
  }
  __syncthreads();

  // stage 1: w = M(xg) on the 18x18 halo tile
  for (int idx = tid; idx < 9 * 324; idx += 256) {
    int t = idx / 324;
    int rem = idx - t * 324;
    int r = rem / 18, c = rem - r * 18;
    int xx = X0 + r - 1, yy = Y0 + c - 1;
    float rw = 0.f;
    if (xx >= 0 && xx < 256 && yy >= 0 && yy < 256) {
      int n = xx * 256 + yy;
      float uc = ux[t][r + 1][c + 1];
      float xp = ux[t][r + 2][c + 1], xm = ux[t][r + 0][c + 1];
      float yp = ux[t][r + 1][c + 2], ym = ux[t][r + 1][c + 0];
      float xpyp = ux[t][r + 2][c + 2], xpym = ux[t][r + 2][c + 0];
      float xmyp = ux[t][r + 0][c + 2], xmym = ux[t][r + 0][c + 0];
      float dx = 0.5f * (xp - xm), dy = 0.5f * (yp - ym);
      float dxx = xp - 2.f * uc + xm, dyy = yp - 2.f * uc + ym;
      float dxy = 0.25f * (xpyp - xpym - xmyp + xmym);
      size_t n9 = (size_t)n * 9 + t;
      float kap = kap_base[n9];
      float m1 = m_base[n9], m2 = m_base[KAP_B + n9];
      float h11 = h_base[n9], h12 = h_base[KAP_B + n9], h22 = h_base[3 * (size_t)KAP_B + n9];
      rw = uc + kap * kap * uc + m1 * dx + m2 * dy
         - (h11 * dxx + 2.f * h12 * dxy + h22 * dyy);
    }
    wsd[t][r][c] = rw;
  }
  __syncthreads();

  // stage 2: v = M(w) on 16x16 center + dot with xg
  const int xx = X0 + ty, yy = Y0 + tx;
  const size_t n9 = ((size_t)(xx * 256 + yy)) * 9;
  float csum = 0.f;
#pragma unroll
  for (int t = 0; t < 9; ++t) {
    float wc = wsd[t][ty + 1][tx + 1];
    float xp = wsd[t][ty + 2][tx + 1], xm = wsd[t][ty + 0][tx + 1];
    float yp = wsd[t][ty + 1][tx + 2], ym = wsd[t][ty + 1][tx + 0];
    float xpyp = wsd[t][ty + 2][tx + 2], xpym = wsd[t][ty + 2][tx + 0];
    float xmyp = wsd[t][ty + 0][tx + 2], xmym = wsd[t][ty + 0][tx + 0];
    float dx = 0.5f * (xp - xm), dy = 0.5f * (yp - ym);
    float dxx = xp - 2.f * wc + xm, dyy = yp - 2.f * wc + ym;
    float dxy = 0.25f * (xpyp - xpym - xmyp + xmym);
    float kap = kap_base[n9 + t];
    float m1 = m_base[n9 + t], m2 = m_base[KAP_B + n9 + t];
    float h11 = h_base[n9 + t], h12 = h_base[KAP_B + n9 + t], h22 = h_base[3 * (size_t)KAP_B + n9 + t];
    float rv = wc + kap * kap * wc + m1 * dx + m2 * dy
             - (h11 * dxx + 2.f * h12 * dxy + h22 * dyy);
    float xgv = ux[t][ty + 2][tx + 2];
    float q = rv;
    if (t > 0) q -= wsd[t - 1][ty + 1][tx + 1];
    if (t < 8) q -= wsd[t + 1][ty + 1][tx + 1];
    if (t > 0 && t < 8) q += xgv;
    csum += xgv * q;
  }
  red[tid] = csum;
  __syncthreads();
  for (int s = 128; s > 0; s >>= 1) {
    if (tid < s) red[tid] += red[tid + s];
    __syncthreads();
  }
  if (tid == 0) atomicAdd(xsum + b, red[0]);
}

extern "C" void kernel_launch(void* const* d_in, const int* in_sizes, int n_in,
                              void* d_out, int out_size, void* d_ws, size_t ws_size,
                              hipStream_t stream) {
  const float* x  = (const float*)d_in[0];
  // d_in[1]=kappa, d_in[2]=m, d_in[3]=H are unused by the reference (shadowed).
  const float* w1 = (const float*)d_in[4];
  const float* w2 = (const float*)d_in[5];
  const float* w3 = (const float*)d_in[6];
  float* out = (float*)d_out;
  float* ws = (float*)d_ws;

  float* xg = ws;                     // 9,437,184 floats
  float* p1 = ws + 9437184;           // 10,485,760 floats
  float* p2 = ws + 19922944;          // 20,971,520 floats

  // zero the x_out accumulator region (first 16 floats)
  hipMemsetAsync(d_out, 0, 16 * sizeof(float), stream);

  transpose_kernel<<<dim3(8, 8, NB * NT), dim3(32, 32), 0, stream>>>(x, xg);
  conv2px<9, 10, true><<<dim3(8, 16, NB), dim3(16, 16), 0, stream>>>(x, w1, p1);
  conv2px<10, 20, true><<<dim3(8, 16, NB), dim3(16, 16), 0, stream>>>(p1, w2, p2);
  conv3_fused<<<dim3(8, 16, NB), dim3(16, 16, 2), 0, stream>>>(p2, w3,
                                                               out + OUT_KAP, out + OUT_M, out + OUT_H);
  m_fused<<<dim3(16, 16, NB), dim3(16, 16), 0, stream>>>(xg, out, out);
}

// Round 4
// 1214.271 us; speedup vs baseline: 1.1400x; 1.1400x over previous
//
#include <hip/hip_runtime.h>
#include <math.h>

#define NB 16
#define NT 9
#define PLANE 65536          // 256*256
#define KAP_B 589824         // 9*PLANE  (per-batch kappa elems)
#define M_B   1179648        // 2*KAP_B
#define H_B   2359296        // 4*KAP_B

// d_out layout (floats): [0,16) x_out | [16, +9437184) kappa | then m (18874368) | then H (37748736)
#define OUT_KAP 16
#define OUT_M   9437200
#define OUT_H   28311568

__device__ __forceinline__ float sp10(float x) {
  float z = 10.0f * x;
  return (fmaxf(z, 0.0f) + log1pf(__expf(-fabsf(z)))) * 0.1f;
}

// ---------------- transpose: xg[b,t,xx,yy] = x[b,t,yy,xx] ----------------
__global__ __launch_bounds__(1024) void transpose_kernel(const float* __restrict__ x,
                                                         float* __restrict__ xg) {
  __shared__ float t_[32][33];
  const int plane = blockIdx.z;                 // b*9+t
  const float* src = x + (size_t)plane * PLANE;
  float* dst = xg + (size_t)plane * PLANE;
  const int x0 = blockIdx.x * 32, y0 = blockIdx.y * 32;
  t_[threadIdx.y][threadIdx.x] = src[(y0 + threadIdx.y) * 256 + x0 + threadIdx.x];
  __syncthreads();
  dst[(x0 + threadIdx.y) * 256 + (y0 + threadIdx.x)] = t_[threadIdx.x][threadIdx.y];
}

// ---------------- 3x3 SAME conv, 2 pixels per thread (conv1/conv2) ----------------
template <int IC, int OC, bool RELU_IN>
__global__ __launch_bounds__(256, 4) void conv2px(const float* __restrict__ in,
                                                  const float* __restrict__ wt,
                                                  float* __restrict__ out) {
  __shared__ float tile[IC][18][35];
  const int b = blockIdx.z;
  const int x0 = blockIdx.x * 32, y0 = blockIdx.y * 16;
  const int tx = threadIdx.x, ty = threadIdx.y;
  const int tid = ty * 16 + tx;
  const float* inb = in + (size_t)b * IC * PLANE;
  for (int idx = tid; idx < IC * 612; idx += 256) {   // 612 = 18*34 staged cols
    int ic = idx / 612;
    int rem = idx - ic * 612;
    int r = rem / 34, c = rem - r * 34;
    int gy = y0 + r - 1, gx = x0 + c - 1;
    float v = 0.f;
    if (gy >= 0 && gy < 256 && gx >= 0 && gx < 256) {
      v = inb[ic * PLANE + gy * 256 + gx];
      if (RELU_IN) v = fmaxf(v, 0.f);
    }
    tile[ic][r][c] = v;
  }
  __syncthreads();
  float acc0[OC], acc1[OC];
#pragma unroll
  for (int oc = 0; oc < OC; ++oc) { acc0[oc] = 0.f; acc1[oc] = 0.f; }
  for (int ic = 0; ic < IC; ++ic) {
    float p[3][4];
#pragma unroll
    for (int r = 0; r < 3; ++r)
#pragma unroll
      for (int c = 0; c < 4; ++c) p[r][c] = tile[ic][ty + r][2 * tx + c];
#pragma unroll
    for (int oc = 0; oc < OC; ++oc) {
      const float* w9 = wt + (oc * IC + ic) * 9;
      acc0[oc] += p[0][0] * w9[0] + p[0][1] * w9[1] + p[0][2] * w9[2]
                + p[1][0] * w9[3] + p[1][1] * w9[4] + p[1][2] * w9[5]
                + p[2][0] * w9[6] + p[2][1] * w9[7] + p[2][2] * w9[8];
      acc1[oc] += p[0][1] * w9[0] + p[0][2] * w9[1] + p[0][3] * w9[2]
                + p[1][1] * w9[3] + p[1][2] * w9[4] + p[1][3] * w9[5]
                + p[2][1] * w9[6] + p[2][2] * w9[7] + p[2][3] * w9[8];
    }
  }
  float* outb = out + (size_t)b * OC * PLANE + (y0 + ty) * 256 + x0 + 2 * tx;
#pragma unroll
  for (int oc = 0; oc < OC; ++oc) {
    float2 v2 = make_float2(acc0[oc], acc1[oc]);
    *reinterpret_cast<float2*>(&outb[oc * PLANE]) = v2;
  }
}

// ---------------- conv3: 4-way channel slice, 2px/thread ----------------
// Slice compute: up to 3 channel runs (B0,N0)(B1,N1)(B2,rest). All acc
// indices compile-time (rule: runtime-indexed arrays -> scratch).
template <int NCH, int B0, int N0, int B1, int N1, int B2>
__device__ __forceinline__ void slice_conv(const float (&tile)[20][10][35],
                                           const float* __restrict__ wt,
                                           int tx, int ty,
                                           float (&a0)[NCH], float (&a1)[NCH]) {
#pragma unroll
  for (int j = 0; j < NCH; ++j) { a0[j] = 0.f; a1[j] = 0.f; }
  for (int ic = 0; ic < 20; ++ic) {
    float p[3][4];
#pragma unroll
    for (int r = 0; r < 3; ++r)
#pragma unroll
      for (int c = 0; c < 4; ++c) p[r][c] = tile[ic][ty + r][2 * tx + c];
#pragma unroll
    for (int j = 0; j < NCH; ++j) {
      const int gc = (j < N0) ? (B0 + j) : (j < N0 + N1) ? (B1 + j - N0) : (B2 + j - N0 - N1);
      const float* w9 = wt + (gc * 20 + ic) * 9;
      a0[j] += p[0][0] * w9[0] + p[0][1] * w9[1] + p[0][2] * w9[2]
             + p[1][0] * w9[3] + p[1][1] * w9[4] + p[1][2] * w9[5]
             + p[2][0] * w9[6] + p[2][1] * w9[7] + p[2][2] * w9[8];
      a1[j] += p[0][1] * w9[0] + p[0][2] * w9[1] + p[0][3] * w9[2]
             + p[1][1] * w9[3] + p[1][2] * w9[4] + p[1][3] * w9[5]
             + p[2][1] * w9[6] + p[2][2] * w9[7] + p[2][3] * w9[8];
    }
  }
}

// H epilogue for t range [T0, T0+NTT): a layout = [g NTT][vx NTT][vy NTT]
template <int T0, int NTT>
__device__ __forceinline__ void h_epilogue(const float (&a0)[3 * NTT], const float (&a1)[3 * NTT],
                                           float* __restrict__ hb) {
  float sg0[NTT], sg1[NTT];
#pragma unroll
  for (int j = 0; j < NTT; ++j) { sg0[j] = sp10(a0[j]); sg1[j] = sp10(a1[j]); }
#pragma unroll
  for (int j = 0; j < NTT; ++j) hb[T0 + j] = sg0[j] + a0[NTT + j] * a0[NTT + j];
#pragma unroll
  for (int j = 0; j < NTT; ++j) hb[9 + T0 + j] = sg1[j] + a1[NTT + j] * a1[NTT + j];
#pragma unroll
  for (int j = 0; j < NTT; ++j) hb[KAP_B + T0 + j] = a0[NTT + j] * a0[2 * NTT + j];
#pragma unroll
  for (int j = 0; j < NTT; ++j) hb[KAP_B + 9 + T0 + j] = a1[NTT + j] * a1[2 * NTT + j];
#pragma unroll
  for (int j = 0; j < NTT; ++j) hb[2 * KAP_B + T0 + j] = a0[NTT + j] * a0[2 * NTT + j];
#pragma unroll
  for (int j = 0; j < NTT; ++j) hb[2 * KAP_B + 9 + T0 + j] = a1[NTT + j] * a1[2 * NTT + j];
#pragma unroll
  for (int j = 0; j < NTT; ++j) hb[3 * KAP_B + T0 + j] = sg0[j] + a0[2 * NTT + j] * a0[2 * NTT + j];
#pragma unroll
  for (int j = 0; j < NTT; ++j) hb[3 * KAP_B + 9 + T0 + j] = sg1[j] + a1[2 * NTT + j] * a1[2 * NTT + j];
}

// Block (16,8,4) = 512 thr, tile 32x8 px, 2px/thread. z slices:
//   z=0: ch 0..13  (kappa t0..8 + m planes 0..4)   14 ch
//   z=1: ch 14..26 (m planes 5..17)                13 ch
//   z=2: H t=0..4  (g 27..31, vx 36..40, vy 45..49) 15 ch
//   z=3: H t=5..8  (g 32..35, vx 41..44, vy 50..53) 12 ch
// Live set ~52 VGPR vs 80 budget at (512,6): no spill (round-3 lesson: the
// (512,6) + acc[54] variant spilled acc to scratch -> +480MB HBM traffic).
__global__ __launch_bounds__(512, 6) void conv3_fused(const float* __restrict__ in,
                                                      const float* __restrict__ wt,
                                                      float* __restrict__ out_kap,
                                                      float* __restrict__ out_m,
                                                      float* __restrict__ out_H) {
  __shared__ float tile[20][10][35];
  const int b = blockIdx.z;
  const int x0 = blockIdx.x * 32, y0 = blockIdx.y * 8;
  const int tx = threadIdx.x, ty = threadIdx.y;
  const int h = __builtin_amdgcn_readfirstlane((int)threadIdx.z);  // z-stride=128thr=2 waves: wave-uniform
  const int tid = (int)threadIdx.z * 128 + ty * 16 + tx;
  const float* inb = in + (size_t)b * 20 * PLANE;
  for (int idx = tid; idx < 20 * 340; idx += 512) {   // 340 = 10 rows * 34 cols
    int ic = idx / 340;
    int rem = idx - ic * 340;
    int r = rem / 34, c = rem - r * 34;
    int gy = y0 + r - 1, gx = x0 + c - 1;
    float v = 0.f;
    if (gy >= 0 && gy < 256 && gx >= 0 && gx < 256)
      v = inb[ic * PLANE + gy * 256 + gx];
    tile[ic][r][c] = v;
  }
  __syncthreads();
  const int n0 = (y0 + ty) * 256 + x0 + 2 * tx;
  if (h == 0) {
    float a0[14], a1[14];
    slice_conv<14, 0, 14, 0, 0, 0>(tile, wt, tx, ty, a0, a1);
    float* kapb = out_kap + (size_t)b * KAP_B;
#pragma unroll
    for (int t = 0; t < 9; ++t)
      *reinterpret_cast<float2*>(&kapb[t * PLANE + n0]) = make_float2(sp10(a0[t]), sp10(a1[t]));
    float* mb = out_m + (size_t)b * M_B;
#pragma unroll
    for (int k = 0; k < 5; ++k)
      *reinterpret_cast<float2*>(&mb[k * PLANE + n0]) = make_float2(a0[9 + k], a1[9 + k]);
  } else if (h == 1) {
    float a0[13], a1[13];
    slice_conv<13, 14, 13, 0, 0, 0>(tile, wt, tx, ty, a0, a1);
    float* mb = out_m + (size_t)b * M_B;
#pragma unroll
    for (int k = 0; k < 13; ++k)
      *reinterpret_cast<float2*>(&mb[(5 + k) * PLANE + n0]) = make_float2(a0[k], a1[k]);
  } else if (h == 2) {
    float a0[15], a1[15];
    slice_conv<15, 27, 5, 36, 5, 45>(tile, wt, tx, ty, a0, a1);
    h_epilogue<0, 5>(a0, a1, out_H + (size_t)b * H_B + (size_t)n0 * 9);
  } else {
    float a0[12], a1[12];
    slice_conv<12, 32, 4, 41, 4, 50>(tile, wt, tx, ty, a0, a1);
    h_epilogue<5, 4>(a0, a1, out_H + (size_t)b * H_B + (size_t)n0 * 9);
  }
}

// ---------------- M operator (two-pass, round-0 structure): r = u + kap^2*u +
// m1*dx + m2*dy - (h11*dxx + 2*h12*dxy + h22*dyy).
// FINAL=false: write w. FINAL=true: compute v, accumulate x_out.
template <bool FINAL>
__global__ __launch_bounds__(256) void m_kernel(const float* __restrict__ u_in,
                                                const float* __restrict__ dout,
                                                const float* __restrict__ xg,
                                                float* __restrict__ w_out,
                                                float* __restrict__ xsum) {
  __shared__ float u[9][18][18];
  __shared__ float red[256];
  const int b = blockIdx.z;
  const int X0 = blockIdx.y * 16;  // xx tile
  const int Y0 = blockIdx.x * 16;  // yy tile
  const int tx = threadIdx.x, ty = threadIdx.y;
  const int tid = ty * 16 + tx;
  const float* ub = u_in + (size_t)b * 9 * PLANE;
  for (int idx = tid; idx < 9 * 324; idx += 256) {
    int t = idx / 324;
    int rem = idx % 324;
    int r = rem / 18, c = rem % 18;
    int xx = X0 + r - 1, yy = Y0 + c - 1;
    float v = 0.f;
    if (xx >= 0 && xx < 256 && yy >= 0 && yy < 256)
      v = ub[t * PLANE + xx * 256 + yy];
    u[t][r][c] = v;
  }
  __syncthreads();
  const int xx = X0 + ty, yy = Y0 + tx;
  const int n = xx * 256 + yy;
  const float* kapb = dout + OUT_KAP + (size_t)b * KAP_B + (size_t)n * 9;
  const float* mb   = dout + OUT_M + (size_t)b * M_B + (size_t)n * 9;
  const float* hbb  = dout + OUT_H + (size_t)b * H_B + (size_t)n * 9;
  float csum = 0.f;
#pragma unroll
  for (int t = 0; t < 9; ++t) {
    float uc = u[t][ty + 1][tx + 1];
    float xp = u[t][ty + 2][tx + 1], xm = u[t][ty + 0][tx + 1];
    float yp = u[t][ty + 1][tx + 2], ym = u[t][ty + 1][tx + 0];
    float xpyp = u[t][ty + 2][tx + 2], xpym = u[t][ty + 2][tx + 0];
    float xmyp = u[t][ty + 0][tx + 2], xmym = u[t][ty + 0][tx + 0];
    float dx = 0.5f * (xp - xm), dy = 0.5f * (yp - ym);
    float dxx = xp - 2.f * uc + xm, dyy = yp - 2.f * uc + ym;
    float dxy = 0.25f * (xpyp - xpym - xmyp + xmym);
    float kap = kapb[t];
    float m1 = mb[t], m2 = mb[KAP_B + t];
    float h11 = hbb[t], h12 = hbb[KAP_B + t], h22 = hbb[3 * KAP_B + t];
    float r = uc + kap * kap * uc + m1 * dx + m2 * dy
            - (h11 * dxx + 2.f * h12 * dxy + h22 * dyy);
    if (!FINAL) {
      w_out[((size_t)(b * 9 + t)) * PLANE + n] = r;
    } else {
      float xgv = xg[((size_t)(b * 9 + t)) * PLANE + n];
      float q = r;
      if (t > 0) q -= u[t - 1][ty + 1][tx + 1];
      if (t < 8) q -= u[t + 1][ty + 1][tx + 1];
      if (t > 0 && t < 8) q += xgv;
      csum += xgv * q;
    }
  }
  if (FINAL) {
    red[tid] = csum;
    __syncthreads();
    for (int s = 128; s > 0; s >>= 1) {
      if (tid < s) red[tid] += red[tid + s];
      __syncthreads();
    }
    if (tid == 0) atomicAdd(xsum + b, red[0]);
  }
}

extern "C" void kernel_launch(void* const* d_in, const int* in_sizes, int n_in,
                              void* d_out, int out_size, void* d_ws, size_t ws_size,
                              hipStream_t stream) {
  const float* x  = (const float*)d_in[0];
  // d_in[1]=kappa, d_in[2]=m, d_in[3]=H are unused by the reference (shadowed).
  const float* w1 = (const float*)d_in[4];
  const float* w2 = (const float*)d_in[5];
  const float* w3 = (const float*)d_in[6];
  float* out = (float*)d_out;
  float* ws = (float*)d_ws;

  float* xg = ws;                     // 9,437,184 floats
  float* p1 = ws + 9437184;           // 10,485,760 floats
  float* p2 = ws + 19922944;          // 20,971,520 floats
  float* wbuf = ws + 9437184;         // reuses p1 (dead after conv2); fits (9.4M <= 10.5M)

  // zero the x_out accumulator region (first 16 floats)
  hipMemsetAsync(d_out, 0, 16 * sizeof(float), stream);

  transpose_kernel<<<dim3(8, 8, NB * NT), dim3(32, 32), 0, stream>>>(x, xg);
  conv2px<9, 10, true><<<dim3(8, 16, NB), dim3(16, 16), 0, stream>>>(x, w1, p1);
  conv2px<10, 20, true><<<dim3(8, 16, NB), dim3(16, 16), 0, stream>>>(p1, w2, p2);
  conv3_fused<<<dim3(8, 32, NB), dim3(16, 8, 4), 0, stream>>>(p2, w3,
                                                              out + OUT_KAP, out + OUT_M, out + OUT_H);
  m_kernel<false><<<dim3(16, 16, NB), dim3(16, 16), 0, stream>>>(xg, out, nullptr, wbuf, nullptr);
  m_kernel<true><<<dim3(16, 16, NB), dim3(16, 16), 0, stream>>>(wbuf, out, xg, nullptr, out);
}